// Round 3
// baseline (526.213 us; speedup 1.0000x reference)
//
#include <hip/hip_runtime.h>
#include <math.h>
#include <stdint.h>

typedef unsigned int u32;
typedef unsigned long long u64;

#define BLOCK 256
#define GROUPS 4
#define PERG 4
#define CHUNK (BLOCK * GROUPS * PERG)  // 4096 rows per block

// ---------------------------------------------------------------------------
// Kernel 1: per-block class histograms (int4) + zero-init of acc/done.
// ---------------------------------------------------------------------------
__global__ void hist_kernel(const int* __restrict__ labels, int N,
                            u32* __restrict__ hist,
                            double* __restrict__ acc, u32* __restrict__ done) {
    __shared__ u32 h[4];
    int tid = threadIdx.x;
    if (tid < 4) h[tid] = 0;
    __syncthreads();
    int base4 = blockIdx.x * (CHUNK / 4);
    const int4* l4 = (const int4*)labels;
    u32 c0 = 0, c1 = 0, c2 = 0, c3 = 0;
#pragma unroll
    for (int j = 0; j < CHUNK / 4 / BLOCK; ++j) {
        int i4 = base4 + j * BLOCK + tid;
        if (4 * i4 + 3 < N) {
            int4 v = l4[i4];
            c0 += (v.x == 0) + (v.y == 0) + (v.z == 0) + (v.w == 0);
            c1 += (v.x == 1) + (v.y == 1) + (v.z == 1) + (v.w == 1);
            c2 += (v.x == 2) + (v.y == 2) + (v.z == 2) + (v.w == 2);
            c3 += (v.x == 3) + (v.y == 3) + (v.z == 3) + (v.w == 3);
        } else {
#pragma unroll
            for (int k = 0; k < 4; ++k) {
                int e = 4 * i4 + k;
                if (e < N) {
                    int l = labels[e];
                    c0 += (l == 0); c1 += (l == 1);
                    c2 += (l == 2); c3 += (l == 3);
                }
            }
        }
    }
    atomicAdd(&h[0], c0);
    atomicAdd(&h[1], c1);
    atomicAdd(&h[2], c2);
    atomicAdd(&h[3], c3);
    __syncthreads();
    if (tid < 4) hist[blockIdx.x * 4 + tid] = h[tid];
    if (blockIdx.x == 0 && tid == 0) { *acc = 0.0; *done = 0u; }
}

// ---------------------------------------------------------------------------
// Kernel 2: fused base-computation + stable rank + margin adjust + scatter +
// analytic sorted labels + loss. Each thread owns 4 consecutive rows in each
// of 4 groups -> int4 label loads, 4x float4 data loads in flight.
// ---------------------------------------------------------------------------
__global__ void __launch_bounds__(BLOCK)
fused_kernel(const float4* __restrict__ data,
             const int* __restrict__ labels, int N,
             const u32* __restrict__ hist, int nb,
             float4* __restrict__ out_data,
             float* __restrict__ out_label,
             double* __restrict__ acc, u32* __restrict__ done,
             float* __restrict__ out_loss) {
    __shared__ u32 s_cnt[GROUPS][4][4];  // [g][wave][class] count -> block-excl prefix
    __shared__ u32 s_red[4][8];          // [wave][pre0..3, tot0..3]
    __shared__ u32 s_b[4];               // cbase[c] + this block's global prefix
    __shared__ u32 s_cb[4];              // class bases
    __shared__ double s_w[4];

    const int tid = threadIdx.x;
    const int lane = tid & 63;
    const int wave = tid >> 6;
    const int myb = blockIdx.x;
    const int base = myb * CHUNK;

    // ---- A0: global base from block histograms (class = tid&3 fixed) ----
    u32 pre = 0, tot = 0;
    const int tote = nb * 4;
    for (int e = tid; e < tote; e += BLOCK) {
        u32 v = hist[e];
        tot += v;
        if ((e >> 2) < myb) pre += v;
    }

    // ---- A1: labels, per-thread counts, wave scans (packed 2x16-bit) ----
    u32 plab[GROUPS], wpreA[GROUPS], wpreB[GROUPS];
    u32 vm = 0;
#pragma unroll
    for (int g = 0; g < GROUPS; ++g) {
        int i0 = base + g * (BLOCK * PERG) + tid * PERG;
        u32 pl = 0;
        u32 cA = 0, cB = 0;  // classes 0,1 | 2,3 in 16-bit halves
        if (i0 + 3 < N) {
            int4 lv = ((const int4*)labels)[i0 >> 2];
            pl = (u32)lv.x | ((u32)lv.y << 2) | ((u32)lv.z << 4) | ((u32)lv.w << 6);
            vm |= 0xFu << (g * 4);
#pragma unroll
            for (int k = 0; k < 4; ++k) {
                int l = (pl >> (2 * k)) & 3;
                if (l < 2) cA += 1u << (16 * l);
                else       cB += 1u << (16 * (l - 2));
            }
        } else {
            for (int k = 0; k < PERG; ++k) {
                int idx = i0 + k;
                if (idx < N) {
                    int l = labels[idx];
                    pl |= (u32)l << (2 * k);
                    vm |= 1u << (g * 4 + k);
                    if (l < 2) cA += 1u << (16 * l);
                    else       cB += 1u << (16 * (l - 2));
                }
            }
        }
        plab[g] = pl;
        u32 a = cA, b = cB;
#pragma unroll
        for (int off = 1; off < 64; off <<= 1) {
            u32 ua = (u32)__shfl_up((int)a, off, 64);
            u32 ub = (u32)__shfl_up((int)b, off, 64);
            if (lane >= off) { a += ua; b += ub; }
        }
        wpreA[g] = a - cA;  // exclusive prefix within wave (packed)
        wpreB[g] = b - cB;
        u32 ta = (u32)__shfl((int)a, 63, 64);
        u32 tb = (u32)__shfl((int)b, 63, 64);
        if (lane == 0) {
            s_cnt[g][wave][0] = ta & 0xFFFF;
            s_cnt[g][wave][1] = ta >> 16;
            s_cnt[g][wave][2] = tb & 0xFFFF;
            s_cnt[g][wave][3] = tb >> 16;
        }
    }
    // wave-reduce A0 partials (class = lane&3)
    {
        u32 p = pre, t = tot;
#pragma unroll
        for (int off = 32; off >= 4; off >>= 1) {
            p += (u32)__shfl_down((int)p, off, 64);
            t += (u32)__shfl_down((int)t, off, 64);
        }
        if (lane < 4) { s_red[wave][lane] = p; s_red[wave][4 + lane] = t; }
    }
    __syncthreads();

    // ---- bases + block-level scan of s_cnt ----
    if (tid < 4) {
        u32 bp = 0, t4[4];
#pragma unroll
        for (int c = 0; c < 4; ++c) t4[c] = 0;
#pragma unroll
        for (int w = 0; w < 4; ++w) {
            bp += s_red[w][tid];
#pragma unroll
            for (int c = 0; c < 4; ++c) t4[c] += s_red[w][4 + c];
        }
        u32 cb = 0;
        for (int c = 0; c < tid; ++c) cb += t4[c];
        s_cb[tid] = cb;
        s_b[tid] = cb + bp;
    }
    {   // wave w scans class w over 16 (g,wave) entries
        int c = wave;
        u32 x = 0, orig = 0;
        if (lane < 16) { orig = s_cnt[lane >> 2][lane & 3][c]; x = orig; }
#pragma unroll
        for (int off = 1; off < 16; off <<= 1) {
            u32 v = (u32)__shfl_up((int)x, off, 64);
            if (lane >= off && lane < 16) x += v;
        }
        if (lane < 16) s_cnt[lane >> 2][lane & 3][c] = x - orig;
    }
    __syncthreads();

    // ---- Phase B: load 4 rows, rank, adjust, scatter, loss ----
    const uint4 sb = *(const uint4*)s_b;
    float loss = 0.f;
    const float INV_M = 0.249999375f;  // 1/4.00001
#pragma unroll
    for (int g = 0; g < GROUPS; ++g) {
        int i0 = base + g * (BLOCK * PERG) + tid * PERG;
        u32 gvm = (vm >> (g * 4)) & 0xF;
        float4 r[PERG];
        if (gvm == 0xF) {
            r[0] = data[i0]; r[1] = data[i0 + 1];
            r[2] = data[i0 + 2]; r[3] = data[i0 + 3];
        } else {
#pragma unroll
            for (int k = 0; k < PERG; ++k)
                if ((gvm >> k) & 1) r[k] = data[i0 + k];
        }
        uint4 bp = *(const uint4*)&s_cnt[g][wave][0];
        u32 pl = plab[g];
        u32 run = 0;
#pragma unroll
        for (int k = 0; k < PERG; ++k) {
            if ((gvm >> k) & 1) {
                int l = (pl >> (2 * k)) & 3;
                u32 self = (run >> (8 * l)) & 0xFF;
                run += 1u << (8 * l);
                u32 wp = (l < 2) ? ((wpreA[g] >> (16 * l)) & 0xFFFF)
                                 : ((wpreB[g] >> (16 * (l - 2))) & 0xFFFF);
                u32 sbl = (l == 0) ? sb.x : (l == 1) ? sb.y : (l == 2) ? sb.z : sb.w;
                u32 bpl = (l == 0) ? bp.x : (l == 1) ? bp.y : (l == 2) ? bp.z : bp.w;
                u32 dst = sbl + bpl + wp + self;
                float4 rr = r[k];
                float v = (l == 0) ? rr.x : (l == 1) ? rr.y : (l == 2) ? rr.z : rr.w;
                float adj = (v > 0.f) ? (v * INV_M - 0.5f) : (v * 4.00001f - 0.5f);
                if (l == 0) rr.x = adj;
                else if (l == 1) rr.y = adj;
                else if (l == 2) rr.z = adj;
                else rr.w = adj;
                out_data[dst] = rr;
                float mx = fmaxf(fmaxf(rr.x, rr.y), fmaxf(rr.z, rr.w));
                float se = __expf(rr.x - mx) + __expf(rr.y - mx) +
                           __expf(rr.z - mx) + __expf(rr.w - mx);
                loss += (mx + __logf(se)) - adj;
            }
        }
    }

    // ---- analytic sorted labels for this block's output range ----
    {
        u32 b1 = s_cb[1], b2 = s_cb[2], b3 = s_cb[3];
        for (int i = tid; i < CHUNK / 4; i += BLOCK) {
            int j = base + i * 4;
            if (j + 3 < N) {
                float4 r;
                u32 j0 = (u32)j;
                r.x = (float)((j0 >= b1) + (j0 >= b2) + (j0 >= b3));
                r.y = (float)((j0 + 1 >= b1) + (j0 + 1 >= b2) + (j0 + 1 >= b3));
                r.z = (float)((j0 + 2 >= b1) + (j0 + 2 >= b2) + (j0 + 2 >= b3));
                r.w = (float)((j0 + 3 >= b1) + (j0 + 3 >= b2) + (j0 + 3 >= b3));
                ((float4*)out_label)[j >> 2] = r;
            } else {
                for (int k = 0; k < 4; ++k) {
                    int jj = j + k;
                    if (jj < N) {
                        u32 ju = (u32)jj;
                        out_label[jj] =
                            (float)((ju >= b1) + (ju >= b2) + (ju >= b3));
                    }
                }
            }
        }
    }

    // ---- loss reduce + ticket finalize ----
    double d = (double)loss;
#pragma unroll
    for (int off = 32; off > 0; off >>= 1) d += __shfl_down(d, off, 64);
    if (lane == 0) s_w[wave] = d;
    __syncthreads();
    if (tid == 0) {
        atomicAdd(acc, s_w[0] + s_w[1] + s_w[2] + s_w[3]);
        __threadfence();
        u32 t = atomicAdd(done, 1u);
        if (t == (u32)(gridDim.x - 1)) {
            __threadfence();
            double totloss = atomicAdd(acc, 0.0);
            *out_loss = (float)(totloss / (double)N);
        }
    }
}

// ---------------------------------------------------------------------------
extern "C" void kernel_launch(void* const* d_in, const int* in_sizes, int n_in,
                              void* d_out, int out_size, void* d_ws,
                              size_t ws_size, hipStream_t stream) {
    const float* data = (const float*)d_in[0];
    const int* labels = (const int*)d_in[1];
    int N = in_sizes[1];
    int nb = (N + CHUNK - 1) / CHUNK;

    u32* hist = (u32*)d_ws;
    double* acc = (double*)(((uintptr_t)(hist + (size_t)nb * 4) + 15) &
                            ~(uintptr_t)15);
    u32* done = (u32*)(acc + 1);

    float* out = (float*)d_out;
    float* out_data = out;                   // N*4
    float* out_label = out + (size_t)N * 4;  // N
    float* out_loss = out + (size_t)N * 5;   // 1

    hist_kernel<<<nb, BLOCK, 0, stream>>>(labels, N, hist, acc, done);
    fused_kernel<<<nb, BLOCK, 0, stream>>>(
        (const float4*)data, labels, N, hist, nb, (float4*)out_data,
        out_label, acc, done, out_loss);
}